// Round 7
// baseline (1349.968 us; speedup 1.0000x reference)
//
#include <hip/hip_runtime.h>
#include <cstdint>
#include <cstddef>

typedef short  short8  __attribute__((ext_vector_type(8)));
typedef float  float4v __attribute__((ext_vector_type(4)));

#define MFMA_B16(a,b,c) __builtin_amdgcn_mfma_f32_16x16x32_bf16(a,b,c,0,0,0)

static constexpr int B_  = 512;
static constexpr int T_  = 256;
static constexpr int DIN = 32;
static constexpr int H_  = 128;
static constexpr int TGT = 64;

// ---- workspace layout (bytes) ----
static constexpr size_t OFF_XFRAG = 0;                          // 8,388,608
static constexpr size_t OFF_EW0   = 8388608;                    // 163,840
static constexpr size_t OFF_EW1LO = OFF_EW0   + 163840;         // 131,072 (kb 0..3)
static constexpr size_t OFF_EW1HI = OFF_EW1LO + 131072;         // 131,072 (kb 4..7)
static constexpr size_t OFF_DW0   = OFF_EW1HI + 131072;         // 163,840
static constexpr size_t OFF_DW1LO = OFF_DW0   + 163840;         // 131,072
static constexpr size_t OFF_DW1HI = OFF_DW1LO + 131072;         // 131,072
static constexpr size_t OFF_LIN   = OFF_DW1HI + 131072;         // 8,192
static constexpr size_t OFF_BIAS  = OFF_LIN   + 8192;           // 8,320
static constexpr size_t WS_NEED   = OFF_BIAS  + 8320;           // ~9.26 MB

__device__ __forceinline__ short f2bf(float f){
  unsigned u = __float_as_uint(f);
  unsigned r = (u + 0x7fffu + ((u>>16)&1u)) >> 16;   // RNE
  return (short)(r & 0xffffu);
}
__device__ __forceinline__ float fast_sigm(float x){
  float e = __expf(-x);
  return __builtin_amdgcn_rcpf(1.f + e);
}
__device__ __forceinline__ float fast_tanh(float x){
  float e = __expf(-2.f*x);                 // tanh = 2*sigm(2x)-1
  return __builtin_amdgcn_rcpf(1.f + e)*2.f - 1.f;
}

// ---------------- prep: x -> bf16 A-fragment tiles ----------------
__global__ void prep_x_kernel(const float* __restrict__ x, short8* __restrict__ xfrag){
  int i = blockIdx.x*256 + threadIdx.x;           // 32*256*64 entries
  if (i >= 32*256*64) return;
  int l    = i & 63;
  int t    = (i >> 6) & 255;
  int bblk = i >> 14;
  int b    = bblk*16 + (l & 15);
  const float* src = x + ((size_t)(b*T_ + t))*DIN + ((l>>4)*8);
  short8 v;
  #pragma unroll
  for (int j=0;j<8;j++) v[j] = f2bf(src[j]);
  xfrag[i] = v;
}

// ---------------- prep: weights -> bf16 B-fragment tiles ----------------
__device__ __forceinline__ void pack160(short8* __restrict__ dst,
                                        const float* __restrict__ Wih,   // (512,32)
                                        const float* __restrict__ Whh,   // (512,128)
                                        int e){
  int nt = e/320; int r = e%320; int kb = r/64; int l = r%64;
  int n  = nt*16 + (l&15);
  short8 v;
  #pragma unroll
  for (int j=0;j<8;j++){
    int k = kb*32 + (l>>4)*8 + j;
    float f = (k < 32) ? Wih[n*32 + k] : Whh[n*128 + (k-32)];
    v[j] = f2bf(f);
  }
  dst[e] = v;
}
// split variant: kb 0..3 -> lo array, kb 4..7 -> hi array
__device__ __forceinline__ void pack256s(short8* __restrict__ dlo, short8* __restrict__ dhi,
                                         const float* __restrict__ Wih,   // (512,128)
                                         const float* __restrict__ Whh,   // (512,128)
                                         int e){
  int nt = e/512; int r = e%512; int kb = r/64; int l = r%64;
  int n  = nt*16 + (l&15);
  short8 v;
  #pragma unroll
  for (int j=0;j<8;j++){
    int k = kb*32 + (l>>4)*8 + j;
    float f = (k < 128) ? Wih[n*128 + k] : Whh[n*128 + (k-128)];
    v[j] = f2bf(f);
  }
  if (kb < 4) dlo[(nt*4 + kb)*64 + l]     = v;
  else        dhi[(nt*4 + (kb-4))*64 + l] = v;
}

__global__ void prep_w_kernel(
    const float* __restrict__ eWih0, const float* __restrict__ eWhh0,
    const float* __restrict__ eWih1, const float* __restrict__ eWhh1,
    const float* __restrict__ dWih0, const float* __restrict__ dWhh0,
    const float* __restrict__ dWih1, const float* __restrict__ dWhh1,
    const float* __restrict__ linW,
    const float* __restrict__ eb0a, const float* __restrict__ eb0b,
    const float* __restrict__ eb1a, const float* __restrict__ eb1b,
    const float* __restrict__ db0a, const float* __restrict__ db0b,
    const float* __restrict__ db1a, const float* __restrict__ db1b,
    const float* __restrict__ linb,
    short8* __restrict__ encW0,
    short8* __restrict__ encW1lo, short8* __restrict__ encW1hi,
    short8* __restrict__ decW0,
    short8* __restrict__ decW1lo, short8* __restrict__ decW1hi,
    short8* __restrict__ linT,  float* __restrict__ biases)
{
  int i = blockIdx.x*256 + threadIdx.x;
  if (i < 10240)       { pack160(encW0, eWih0, eWhh0, i); }
  else if (i < 26624)  { pack256s(encW1lo, encW1hi, eWih1, eWhh1, i-10240); }
  else if (i < 36864)  { pack160(decW0, dWih0, dWhh0, i-26624); }
  else if (i < 53248)  { pack256s(decW1lo, decW1hi, dWih1, dWhh1, i-36864); }
  else if (i < 53760)  {
    int e = i - 53248;                       // lin: 2nt * 4kb * 64
    int nt = e/256; int r = e%256; int kb = r/64; int l = r%64;
    int n = nt*16 + (l&15);
    short8 v;
    #pragma unroll
    for (int j=0;j<8;j++){
      int k = kb*32 + (l>>4)*8 + j;          // k < 128
      v[j] = f2bf(linW[n*128 + k]);
    }
    linT[e] = v;
  }
  else if (i < 55840)  {
    int e = i - 53760;                       // 2080 bias entries
    float v;
    if      (e < 512)  v = eb0a[e]       + eb0b[e];
    else if (e < 1024) v = eb1a[e-512]   + eb1b[e-512];
    else if (e < 1536) v = db0a[e-1024]  + db0b[e-1024];
    else if (e < 2048) v = db1a[e-1536]  + db1b[e-1536];
    else               v = linb[e-2048];
    biases[e] = v;
  }
}

// ---------------- main fused persistent kernel ----------------
// 32 blocks (16 batch rows each) x 256 threads (4 waves, 1 wave/SIMD,
// 512-VGPR budget). Wave w owns 8 gate n-tiles: nt = 8*gate + 2w + p
// (gate in {i,f,g,o}, p in {0,1}) = the full gate set of hidden slice
// [32w,32w+32) for BOTH layers. Weight placement: W0 h-part (128 regs) +
// W1 full (256 regs) in VGPRs -> zero per-step LDS weight traffic; only
// W0 x-part (32 KB) + lin weights stay in LDS. Encoder is software-
// pipelined (L0(i) + L1(i-1) per phase, 1 barrier/step).
__global__ __launch_bounds__(256, 1) void lstm_main_kernel(
    const short8* __restrict__ xfrag,
    const short8* __restrict__ encW0,
    const short8* __restrict__ encW1lo, const short8* __restrict__ encW1hi,
    const short8* __restrict__ decW0,
    const short8* __restrict__ decW1lo, const short8* __restrict__ decW1hi,
    const short8* __restrict__ linT,  const float* __restrict__ biases,
    float* __restrict__ out)
{
  __shared__ __align__(16) short8 Wx[2048];       // W0 x-part, 32 KB (enc->dec restage)
  __shared__ __align__(16) short Abuf[16][520];   // h state, parity double-buffered
  __shared__ __align__(16) short inpA[16][40];    // decoder input frame
  __shared__ __align__(16) short8 Wlin[512];      // projection weights

  const int tid  = threadIdx.x;
  const int w    = tid >> 6;
  const int l    = tid & 63;
  const int col  = l & 15;
  const int lq   = l >> 4;
  const int bblk = blockIdx.x;

  // stage W0 x-part into LDS + zero h state
  for (int i = tid; i < 2048; i += 256) Wx[i] = encW0[(size_t)(i>>6)*320 + (i&63)];
  for (int i = tid; i < 16*520; i += 256) ((short*)Abuf)[i] = 0;

  const int wxbase = 2*w*64 + l;   // + (j>>1)*512 + (j&1)*64 per tile

  // ---- persistent weight registers (encoder first) ----
  short8 W0h[8][4];   // L0 h-part: tile j, kb 1..4
  short8 W1r[8][8];   // L1 full:   tile j, kb 0..7
  float  bs0[8], bs1[8];
  #pragma unroll
  for (int j=0;j<8;j++){
    int nt = 8*(j>>1) + 2*w + (j&1);
    #pragma unroll
    for (int kb=0;kb<4;kb++) W0h[j][kb] = encW0  [(size_t)nt*320 + (size_t)(kb+1)*64 + l];
    #pragma unroll
    for (int kb=0;kb<4;kb++) W1r[j][kb]   = encW1lo[(size_t)nt*256 + (size_t)kb*64 + l];
    #pragma unroll
    for (int kb=0;kb<4;kb++) W1r[j][kb+4] = encW1hi[(size_t)nt*256 + (size_t)kb*64 + l];
    bs0[j] = biases[      nt*16 + col];
    bs1[j] = biases[512 + nt*16 + col];
  }

  float c0[8] = {0,0,0,0,0,0,0,0};
  float c1[8] = {0,0,0,0,0,0,0,0};

  const short8* xf = xfrag + (size_t)bblk*T_*64 + l;
  short8 a0 = xf[0];
  __syncthreads();

  // ---- peel: i=0, L0 only (h0(-1)=0 -> only x term + bias) ----
  {
    float4v acc0[8];
    #pragma unroll
    for (int j=0;j<8;j++){
      float4v a = {bs0[j],bs0[j],bs0[j],bs0[j]};
      acc0[j] = MFMA_B16(a0, Wx[wxbase + (j>>1)*512 + (j&1)*64], a);
    }
    a0 = xf[64];
    #pragma unroll
    for (int p=0;p<2;p++)
      #pragma unroll
      for (int q=0;q<4;q++){
        float cc = fast_sigm(acc0[p][q])*fast_tanh(acc0[4+p][q]);   // f*c0 = 0
        c0[p*4+q] = cc;
        Abuf[lq*4+q][0 + (2*w+p)*16 + col] = f2bf(fast_sigm(acc0[6+p][q])*fast_tanh(cc));
      }
    __syncthreads();
  }

  // ---- main: i = 1..255 : L0(i) + L1(i-1) ----
  #pragma unroll 2
  for (int i = 1; i < T_; i++){
    const int p_h0_r = ((i-1)&1)*128;          // h0(i-1) — shared by L0 and L1
    const int p_h0_w = (i&1)*128;              // h0(i)
    const int p_h1_r = 256 + (i&1)*128;        // h1(i-2)
    const int p_h1_w = 256 + ((i-1)&1)*128;    // h1(i-1)

    short8 hp[4], h1p[4];
    #pragma unroll
    for (int kb=0;kb<4;kb++) hp[kb]  = *(const short8*)&Abuf[col][p_h0_r + kb*32 + lq*8];
    #pragma unroll
    for (int kb=0;kb<4;kb++) h1p[kb] = *(const short8*)&Abuf[col][p_h1_r + kb*32 + lq*8];

    // ---- L0 MFMAs ----
    float4v acc0[8];
    #pragma unroll
    for (int j=0;j<8;j++){
      float4v a = {bs0[j],bs0[j],bs0[j],bs0[j]};
      a = MFMA_B16(a0, Wx[wxbase + (j>>1)*512 + (j&1)*64], a);
      #pragma unroll
      for (int kb=0;kb<4;kb++) a = MFMA_B16(hp[kb], W0h[j][kb], a);
      acc0[j] = a;
    }
    a0 = xf[(size_t)((i+1 < T_) ? i+1 : i)*64];   // prefetch next frame
    // ---- act0 (acc0 dies here; keeps peak regs < 512) ----
    #pragma unroll
    for (int p=0;p<2;p++)
      #pragma unroll
      for (int q=0;q<4;q++){
        float cc = fast_sigm(acc0[2+p][q])*c0[p*4+q]
                 + fast_sigm(acc0[p][q])*fast_tanh(acc0[4+p][q]);
        c0[p*4+q] = cc;
        Abuf[lq*4+q][p_h0_w + (2*w+p)*16 + col] = f2bf(fast_sigm(acc0[6+p][q])*fast_tanh(cc));
      }

    // ---- L1 MFMAs ----
    float4v acc1[8];
    #pragma unroll
    for (int j=0;j<8;j++){
      float4v a = {bs1[j],bs1[j],bs1[j],bs1[j]};
      #pragma unroll
      for (int kb=0;kb<4;kb++) a = MFMA_B16(hp[kb],  W1r[j][kb],   a);
      #pragma unroll
      for (int kb=0;kb<4;kb++) a = MFMA_B16(h1p[kb], W1r[j][kb+4], a);
      acc1[j] = a;
    }
    // ---- act1 ----
    #pragma unroll
    for (int p=0;p<2;p++)
      #pragma unroll
      for (int q=0;q<4;q++){
        float cc = fast_sigm(acc1[2+p][q])*c1[p*4+q]
                 + fast_sigm(acc1[p][q])*fast_tanh(acc1[4+p][q]);
        c1[p*4+q] = cc;
        Abuf[lq*4+q][p_h1_w + (2*w+p)*16 + col] = f2bf(fast_sigm(acc1[6+p][q])*fast_tanh(cc));
      }
    __syncthreads();
  }

  // ---- epilogue: L1 for t = 255 ----
  {
    const int p_h0_r = 128;        // h0(255), parity 1
    const int p_h1_r = 256 + 0;    // h1(254), parity 0
    const int p_h1_w = 256 + 128;  // h1(255), parity 1
    short8 hp[4], h1p[4];
    #pragma unroll
    for (int kb=0;kb<4;kb++) hp[kb]  = *(const short8*)&Abuf[col][p_h0_r + kb*32 + lq*8];
    #pragma unroll
    for (int kb=0;kb<4;kb++) h1p[kb] = *(const short8*)&Abuf[col][p_h1_r + kb*32 + lq*8];
    float4v acc1[8];
    #pragma unroll
    for (int j=0;j<8;j++){
      float4v a = {bs1[j],bs1[j],bs1[j],bs1[j]};
      #pragma unroll
      for (int kb=0;kb<4;kb++) a = MFMA_B16(hp[kb],  W1r[j][kb],   a);
      #pragma unroll
      for (int kb=0;kb<4;kb++) a = MFMA_B16(h1p[kb], W1r[j][kb+4], a);
      acc1[j] = a;
    }
    #pragma unroll
    for (int p=0;p<2;p++)
      #pragma unroll
      for (int q=0;q<4;q++){
        float cc = fast_sigm(acc1[2+p][q])*c1[p*4+q]
                 + fast_sigm(acc1[p][q])*fast_tanh(acc1[4+p][q]);
        c1[p*4+q] = cc;
        Abuf[lq*4+q][p_h1_w + (2*w+p)*16 + col] = f2bf(fast_sigm(acc1[6+p][q])*fast_tanh(cc));
      }
    __syncthreads();
  }

  // ---- swap weights to decoder ----
  for (int i = tid; i < 2048; i += 256) Wx[i] = decW0[(size_t)(i>>6)*320 + (i&63)];
  for (int i = tid; i < 512;  i += 256) Wlin[i] = linT[i];
  #pragma unroll
  for (int j=0;j<8;j++){
    int nt = 8*(j>>1) + 2*w + (j&1);
    #pragma unroll
    for (int kb=0;kb<4;kb++) W0h[j][kb] = decW0  [(size_t)nt*320 + (size_t)(kb+1)*64 + l];
    #pragma unroll
    for (int kb=0;kb<4;kb++) W1r[j][kb]   = decW1lo[(size_t)nt*256 + (size_t)kb*64 + l];
    #pragma unroll
    for (int kb=0;kb<4;kb++) W1r[j][kb+4] = decW1hi[(size_t)nt*256 + (size_t)kb*64 + l];
    bs0[j] = biases[1024 + nt*16 + col];
    bs1[j] = biases[1536 + nt*16 + col];
  }
  float blin = (w < 2) ? biases[2048 + w*16 + col] : 0.f;
  if (w == 0){
    *(short8*)&inpA[col][lq*8] = xf[(size_t)(T_-1)*64];   // dec input 0 = x[:,-1,:]
  }
  __syncthreads();

  // ---------------- decoder: 64 steps, 3 phases ----------------
  // enc left h0/h1 at parity 1 -> dec td reads parity (td+1)&1, writes td&1.
  #pragma unroll 2
  for (int td = 0; td < TGT; td++){
    const int h0r = ((td+1)&1) * 128;
    const int h0w = 128 - h0r;
    const int h1r = 256 + h0r;
    const int h1w = 256 + h0w;

    // ---- phase 1: layer 0 ----
    short8 a0d = *(const short8*)&inpA[col][lq*8];
    short8 hp[4];
    #pragma unroll
    for (int kb=0;kb<4;kb++) hp[kb] = *(const short8*)&Abuf[col][h0r + kb*32 + lq*8];
    float4v acc0[8];
    #pragma unroll
    for (int j=0;j<8;j++){
      float4v a = {bs0[j],bs0[j],bs0[j],bs0[j]};
      a = MFMA_B16(a0d, Wx[wxbase + (j>>1)*512 + (j&1)*64], a);
      #pragma unroll
      for (int kb=0;kb<4;kb++) a = MFMA_B16(hp[kb], W0h[j][kb], a);
      acc0[j] = a;
    }
    #pragma unroll
    for (int p=0;p<2;p++)
      #pragma unroll
      for (int q=0;q<4;q++){
        float cc = fast_sigm(acc0[2+p][q])*c0[p*4+q]
                 + fast_sigm(acc0[p][q])*fast_tanh(acc0[4+p][q]);
        c0[p*4+q] = cc;
        Abuf[lq*4+q][h0w + (2*w+p)*16 + col] = f2bf(fast_sigm(acc0[6+p][q])*fast_tanh(cc));
      }
    __syncthreads();

    // ---- phase 2: layer 1 ----
    short8 a1lo[4], a1hi[4];
    #pragma unroll
    for (int kb=0;kb<4;kb++) a1lo[kb] = *(const short8*)&Abuf[col][h0w + kb*32 + lq*8];
    #pragma unroll
    for (int kb=0;kb<4;kb++) a1hi[kb] = *(const short8*)&Abuf[col][h1r + kb*32 + lq*8];
    float4v acc1[8];
    #pragma unroll
    for (int j=0;j<8;j++){
      float4v a = {bs1[j],bs1[j],bs1[j],bs1[j]};
      #pragma unroll
      for (int kb=0;kb<4;kb++) a = MFMA_B16(a1lo[kb], W1r[j][kb],   a);
      #pragma unroll
      for (int kb=0;kb<4;kb++) a = MFMA_B16(a1hi[kb], W1r[j][kb+4], a);
      acc1[j] = a;
    }
    #pragma unroll
    for (int p=0;p<2;p++)
      #pragma unroll
      for (int q=0;q<4;q++){
        float cc = fast_sigm(acc1[2+p][q])*c1[p*4+q]
                 + fast_sigm(acc1[p][q])*fast_tanh(acc1[4+p][q]);
        c1[p*4+q] = cc;
        Abuf[lq*4+q][h1w + (2*w+p)*16 + col] = f2bf(fast_sigm(acc1[6+p][q])*fast_tanh(cc));
      }
    __syncthreads();

    // ---- phase 3: projection + feedback ----
    if (w < 2){
      short8 hf[4];
      #pragma unroll
      for (int kb=0;kb<4;kb++) hf[kb] = *(const short8*)&Abuf[col][h1w + kb*32 + lq*8];
      float4v a = {blin,blin,blin,blin};
      #pragma unroll
      for (int kb=0;kb<4;kb++) a = MFMA_B16(hf[kb], Wlin[(w*4+kb)*64 + l], a);
      #pragma unroll
      for (int q=0;q<4;q++){
        float v = a[q];
        int b = bblk*16 + lq*4 + q;
        out[((size_t)b*TGT + td)*DIN + (w*16 + col)] = v;
        inpA[lq*4+q][w*16 + col] = f2bf(v);
      }
    }
    __syncthreads();
  }
}

// ---------------- host ----------------
extern "C" void kernel_launch(void* const* d_in, const int* in_sizes, int n_in,
                              void* d_out, int out_size, void* d_ws, size_t ws_size,
                              hipStream_t stream) {
  const float* x      = (const float*)d_in[0];
  const float* eWih0  = (const float*)d_in[2];
  const float* eWhh0  = (const float*)d_in[3];
  const float* eb0a   = (const float*)d_in[4];
  const float* eb0b   = (const float*)d_in[5];
  const float* eWih1  = (const float*)d_in[6];
  const float* eWhh1  = (const float*)d_in[7];
  const float* eb1a   = (const float*)d_in[8];
  const float* eb1b   = (const float*)d_in[9];
  const float* dWih0  = (const float*)d_in[10];
  const float* dWhh0  = (const float*)d_in[11];
  const float* db0a   = (const float*)d_in[12];
  const float* db0b   = (const float*)d_in[13];
  const float* dWih1  = (const float*)d_in[14];
  const float* dWhh1  = (const float*)d_in[15];
  const float* db1a   = (const float*)d_in[16];
  const float* db1b   = (const float*)d_in[17];
  const float* linW   = (const float*)d_in[18];
  const float* linb   = (const float*)d_in[19];

  char* ws = (char*)d_ws;
  short8* xfrag   = (short8*)(ws + OFF_XFRAG);
  short8* encW0   = (short8*)(ws + OFF_EW0);
  short8* encW1lo = (short8*)(ws + OFF_EW1LO);
  short8* encW1hi = (short8*)(ws + OFF_EW1HI);
  short8* decW0   = (short8*)(ws + OFF_DW0);
  short8* decW1lo = (short8*)(ws + OFF_DW1LO);
  short8* decW1hi = (short8*)(ws + OFF_DW1HI);
  short8* linT    = (short8*)(ws + OFF_LIN);
  float*  biases  = (float*)(ws + OFF_BIAS);

  prep_x_kernel<<<2048, 256, 0, stream>>>(x, xfrag);
  prep_w_kernel<<<219, 256, 0, stream>>>(
      eWih0,eWhh0,eWih1,eWhh1,dWih0,dWhh0,dWih1,dWhh1,linW,
      eb0a,eb0b,eb1a,eb1b,db0a,db0b,db1a,db1b,linb,
      encW0,encW1lo,encW1hi,decW0,decW1lo,decW1hi,linT,biases);
  lstm_main_kernel<<<32, 256, 0, stream>>>(
      xfrag, encW0, encW1lo, encW1hi, decW0, decW1lo, decW1hi,
      linT, biases, (float*)d_out);
}

// Round 8
// 1209.723 us; speedup vs baseline: 1.1159x; 1.1159x over previous
//
#include <hip/hip_runtime.h>
#include <cstdint>
#include <cstddef>

typedef short  short8  __attribute__((ext_vector_type(8)));
typedef float  float4v __attribute__((ext_vector_type(4)));
typedef int    int4v   __attribute__((ext_vector_type(4)));

#define MFMA_B16(a,b,c) __builtin_amdgcn_mfma_f32_16x16x32_bf16(a,b,c,0,0,0)

static constexpr int B_  = 512;
static constexpr int T_  = 256;
static constexpr int DIN = 32;
static constexpr int H_  = 128;
static constexpr int TGT = 64;

// ---- workspace layout (bytes) ----
static constexpr size_t OFF_XFRAG = 0;                          // 8,388,608
static constexpr size_t OFF_EW0   = 8388608;                    // 163,840
static constexpr size_t OFF_EW1LO = OFF_EW0   + 163840;         // 131,072 (kb 0..3)
static constexpr size_t OFF_EW1HI = OFF_EW1LO + 131072;         // 131,072 (kb 4..7)
static constexpr size_t OFF_DW0   = OFF_EW1HI + 131072;         // 163,840
static constexpr size_t OFF_DW1LO = OFF_DW0   + 163840;         // 131,072
static constexpr size_t OFF_DW1HI = OFF_DW1LO + 131072;         // 131,072
static constexpr size_t OFF_LIN   = OFF_DW1HI + 131072;         // 8,192
static constexpr size_t OFF_BIAS  = OFF_LIN   + 8192;           // 8,320
static constexpr size_t WS_NEED   = OFF_BIAS  + 8320;           // ~9.26 MB

__device__ __forceinline__ short f2bf(float f){
  unsigned u = __float_as_uint(f);
  unsigned r = (u + 0x7fffu + ((u>>16)&1u)) >> 16;   // RNE
  return (short)(r & 0xffffu);
}
__device__ __forceinline__ float fast_sigm(float x){
  float e = __expf(-x);
  return __builtin_amdgcn_rcpf(1.f + e);
}
__device__ __forceinline__ float fast_tanh(float x){
  float e = __expf(-2.f*x);                 // tanh = 2*sigm(2x)-1
  return __builtin_amdgcn_rcpf(1.f + e)*2.f - 1.f;
}
__device__ __forceinline__ short8 as_s8(int4v v){
  union { int4v i; short8 s; } u; u.i = v; return u.s;
}

// ---------------- prep: x -> bf16 A-fragment tiles ----------------
__global__ void prep_x_kernel(const float* __restrict__ x, short8* __restrict__ xfrag){
  int i = blockIdx.x*256 + threadIdx.x;           // 32*256*64 entries
  if (i >= 32*256*64) return;
  int l    = i & 63;
  int t    = (i >> 6) & 255;
  int bblk = i >> 14;
  int b    = bblk*16 + (l & 15);
  const float* src = x + ((size_t)(b*T_ + t))*DIN + ((l>>4)*8);
  short8 v;
  #pragma unroll
  for (int j=0;j<8;j++) v[j] = f2bf(src[j]);
  xfrag[i] = v;
}

// ---------------- prep: weights -> bf16 B-fragment tiles ----------------
__device__ __forceinline__ void pack160(short8* __restrict__ dst,
                                        const float* __restrict__ Wih,   // (512,32)
                                        const float* __restrict__ Whh,   // (512,128)
                                        int e){
  int nt = e/320; int r = e%320; int kb = r/64; int l = r%64;
  int n  = nt*16 + (l&15);
  short8 v;
  #pragma unroll
  for (int j=0;j<8;j++){
    int k = kb*32 + (l>>4)*8 + j;
    float f = (k < 32) ? Wih[n*32 + k] : Whh[n*128 + (k-32)];
    v[j] = f2bf(f);
  }
  dst[e] = v;
}
// split variant: kb 0..3 -> lo array, kb 4..7 -> hi array
__device__ __forceinline__ void pack256s(short8* __restrict__ dlo, short8* __restrict__ dhi,
                                         const float* __restrict__ Wih,   // (512,128)
                                         const float* __restrict__ Whh,   // (512,128)
                                         int e){
  int nt = e/512; int r = e%512; int kb = r/64; int l = r%64;
  int n  = nt*16 + (l&15);
  short8 v;
  #pragma unroll
  for (int j=0;j<8;j++){
    int k = kb*32 + (l>>4)*8 + j;
    float f = (k < 128) ? Wih[n*128 + k] : Whh[n*128 + (k-128)];
    v[j] = f2bf(f);
  }
  if (kb < 4) dlo[(nt*4 + kb)*64 + l]     = v;
  else        dhi[(nt*4 + (kb-4))*64 + l] = v;
}

__global__ void prep_w_kernel(
    const float* __restrict__ eWih0, const float* __restrict__ eWhh0,
    const float* __restrict__ eWih1, const float* __restrict__ eWhh1,
    const float* __restrict__ dWih0, const float* __restrict__ dWhh0,
    const float* __restrict__ dWih1, const float* __restrict__ dWhh1,
    const float* __restrict__ linW,
    const float* __restrict__ eb0a, const float* __restrict__ eb0b,
    const float* __restrict__ eb1a, const float* __restrict__ eb1b,
    const float* __restrict__ db0a, const float* __restrict__ db0b,
    const float* __restrict__ db1a, const float* __restrict__ db1b,
    const float* __restrict__ linb,
    short8* __restrict__ encW0,
    short8* __restrict__ encW1lo, short8* __restrict__ encW1hi,
    short8* __restrict__ decW0,
    short8* __restrict__ decW1lo, short8* __restrict__ decW1hi,
    short8* __restrict__ linT,  float* __restrict__ biases)
{
  int i = blockIdx.x*256 + threadIdx.x;
  if (i < 10240)       { pack160(encW0, eWih0, eWhh0, i); }
  else if (i < 26624)  { pack256s(encW1lo, encW1hi, eWih1, eWhh1, i-10240); }
  else if (i < 36864)  { pack160(decW0, dWih0, dWhh0, i-26624); }
  else if (i < 53248)  { pack256s(decW1lo, decW1hi, dWih1, dWhh1, i-36864); }
  else if (i < 53760)  {
    int e = i - 53248;                       // lin: 2nt * 4kb * 64
    int nt = e/256; int r = e%256; int kb = r/64; int l = r%64;
    int n = nt*16 + (l&15);
    short8 v;
    #pragma unroll
    for (int j=0;j<8;j++){
      int k = kb*32 + (l>>4)*8 + j;          // k < 128
      v[j] = f2bf(linW[n*128 + k]);
    }
    linT[e] = v;
  }
  else if (i < 55840)  {
    int e = i - 53760;                       // 2080 bias entries
    float v;
    if      (e < 512)  v = eb0a[e]       + eb0b[e];
    else if (e < 1024) v = eb1a[e-512]   + eb1b[e-512];
    else if (e < 1536) v = db0a[e-1024]  + db0b[e-1024];
    else if (e < 2048) v = db1a[e-1536]  + db1b[e-1536];
    else               v = linb[e-2048];
    biases[e] = v;
  }
}

// ---------------- main fused persistent kernel ----------------
// 32 blocks (16 batch rows each) x 256 threads (4 waves, 1 wave/SIMD).
// Wave w owns 8 gate n-tiles: nt = 8*gate + 2w + p (full gate set of
// hidden slice [32w,32w+32)) for BOTH layers.
// Register budget (per-wave HW caps: 256 arch VGPR + 256 AGPR):
//   W1 full (64 short8 = 256 regs) -> pinned to AGPRs via "+a" asm;
//   legal as MFMA B operands on gfx950 (unified file).
//   W0 h-part (128 regs) + working set (~100) -> arch VGPRs.
//   W0 x-part (32 KB) + lin -> LDS.
// => zero per-step LDS weight traffic for W1, zero scratch spill.
__global__ __launch_bounds__(256, 1) void lstm_main_kernel(
    const short8* __restrict__ xfrag,
    const short8* __restrict__ encW0,
    const short8* __restrict__ encW1lo, const short8* __restrict__ encW1hi,
    const short8* __restrict__ decW0,
    const short8* __restrict__ decW1lo, const short8* __restrict__ decW1hi,
    const short8* __restrict__ linT,  const float* __restrict__ biases,
    float* __restrict__ out)
{
  __shared__ __align__(16) short8 Wx[2048];       // W0 x-part, 32 KB
  __shared__ __align__(16) short Abuf[16][520];   // h state, parity double-buffered
  __shared__ __align__(16) short inpA[16][40];    // decoder input frame
  __shared__ __align__(16) short8 Wlin[512];      // projection weights

  const int tid  = threadIdx.x;
  const int w    = tid >> 6;
  const int l    = tid & 63;
  const int col  = l & 15;
  const int lq   = l >> 4;
  const int bblk = blockIdx.x;

  // stage W0 x-part into LDS + zero h state
  for (int i = tid; i < 2048; i += 256) Wx[i] = encW0[(size_t)(i>>6)*320 + (i&63)];
  for (int i = tid; i < 16*520; i += 256) ((short*)Abuf)[i] = 0;

  const int wxbase = 2*w*64 + l;   // + (j>>1)*512 + (j&1)*64 per tile

  // ---- persistent weight registers (encoder first) ----
  short8 W0h[8][4];   // L0 h-part: tile j, kb 1..4  (arch VGPRs)
  int4v  W1r[8][8];   // L1 full:   tile j, kb 0..7  (pinned to AGPRs)
  float  bs0[8], bs1[8];
  #pragma unroll
  for (int j=0;j<8;j++){
    int nt = 8*(j>>1) + 2*w + (j&1);
    #pragma unroll
    for (int kb=0;kb<4;kb++) W0h[j][kb] = encW0[(size_t)nt*320 + (size_t)(kb+1)*64 + l];
    #pragma unroll
    for (int kb=0;kb<4;kb++) W1r[j][kb]   = ((const int4v*)encW1lo)[(size_t)nt*256 + (size_t)kb*64 + l];
    #pragma unroll
    for (int kb=0;kb<4;kb++) W1r[j][kb+4] = ((const int4v*)encW1hi)[(size_t)nt*256 + (size_t)kb*64 + l];
    bs0[j] = biases[      nt*16 + col];
    bs1[j] = biases[512 + nt*16 + col];
  }
  // pin W1 into AGPRs (256 accum regs/wave; frees the arch file)
  #pragma unroll
  for (int j=0;j<8;j++)
    #pragma unroll
    for (int kb=0;kb<8;kb++)
      asm volatile("" : "+a"(W1r[j][kb]));

  float c0[8] = {0,0,0,0,0,0,0,0};
  float c1[8] = {0,0,0,0,0,0,0,0};

  const short8* xf = xfrag + (size_t)bblk*T_*64 + l;
  short8 a0 = xf[0];
  __syncthreads();

  // ---- peel: i=0, L0 only (h0(-1)=0 -> only x term + bias) ----
  {
    float4v acc0[8];
    #pragma unroll
    for (int j=0;j<8;j++){
      float4v a = {bs0[j],bs0[j],bs0[j],bs0[j]};
      acc0[j] = MFMA_B16(a0, Wx[wxbase + (j>>1)*512 + (j&1)*64], a);
    }
    a0 = xf[64];
    #pragma unroll
    for (int p=0;p<2;p++)
      #pragma unroll
      for (int q=0;q<4;q++){
        float cc = fast_sigm(acc0[p][q])*fast_tanh(acc0[4+p][q]);   // f*c0 = 0
        c0[p*4+q] = cc;
        Abuf[lq*4+q][0 + (2*w+p)*16 + col] = f2bf(fast_sigm(acc0[6+p][q])*fast_tanh(cc));
      }
    __syncthreads();
  }

  // ---- main: i = 1..255 : L0(i) + L1(i-1) ----
  #pragma unroll 2
  for (int i = 1; i < T_; i++){
    const int p_h0_r = ((i-1)&1)*128;          // h0(i-1) — shared by L0 and L1
    const int p_h0_w = (i&1)*128;              // h0(i)
    const int p_h1_r = 256 + (i&1)*128;        // h1(i-2)
    const int p_h1_w = 256 + ((i-1)&1)*128;    // h1(i-1)

    short8 hp[4], h1p[4];
    #pragma unroll
    for (int kb=0;kb<4;kb++) hp[kb]  = *(const short8*)&Abuf[col][p_h0_r + kb*32 + lq*8];
    #pragma unroll
    for (int kb=0;kb<4;kb++) h1p[kb] = *(const short8*)&Abuf[col][p_h1_r + kb*32 + lq*8];

    // ---- L0 MFMAs ----
    float4v acc0[8];
    #pragma unroll
    for (int j=0;j<8;j++){
      float4v a = {bs0[j],bs0[j],bs0[j],bs0[j]};
      a = MFMA_B16(a0, Wx[wxbase + (j>>1)*512 + (j&1)*64], a);
      #pragma unroll
      for (int kb=0;kb<4;kb++) a = MFMA_B16(hp[kb], W0h[j][kb], a);
      acc0[j] = a;
    }
    a0 = xf[(size_t)((i+1 < T_) ? i+1 : i)*64];   // prefetch next frame
    // ---- act0 (acc0 dies here; keeps peak arch regs < 256) ----
    #pragma unroll
    for (int p=0;p<2;p++)
      #pragma unroll
      for (int q=0;q<4;q++){
        float cc = fast_sigm(acc0[2+p][q])*c0[p*4+q]
                 + fast_sigm(acc0[p][q])*fast_tanh(acc0[4+p][q]);
        c0[p*4+q] = cc;
        Abuf[lq*4+q][p_h0_w + (2*w+p)*16 + col] = f2bf(fast_sigm(acc0[6+p][q])*fast_tanh(cc));
      }

    // ---- L1 MFMAs (B operands from AGPRs) ----
    float4v acc1[8];
    #pragma unroll
    for (int j=0;j<8;j++){
      float4v a = {bs1[j],bs1[j],bs1[j],bs1[j]};
      #pragma unroll
      for (int kb=0;kb<4;kb++) a = MFMA_B16(hp[kb],  as_s8(W1r[j][kb]),   a);
      #pragma unroll
      for (int kb=0;kb<4;kb++) a = MFMA_B16(h1p[kb], as_s8(W1r[j][kb+4]), a);
      acc1[j] = a;
    }
    // ---- act1 ----
    #pragma unroll
    for (int p=0;p<2;p++)
      #pragma unroll
      for (int q=0;q<4;q++){
        float cc = fast_sigm(acc1[2+p][q])*c1[p*4+q]
                 + fast_sigm(acc1[p][q])*fast_tanh(acc1[4+p][q]);
        c1[p*4+q] = cc;
        Abuf[lq*4+q][p_h1_w + (2*w+p)*16 + col] = f2bf(fast_sigm(acc1[6+p][q])*fast_tanh(cc));
      }
    __syncthreads();
  }

  // ---- epilogue: L1 for t = 255 ----
  {
    const int p_h0_r = 128;        // h0(255), parity 1
    const int p_h1_r = 256 + 0;    // h1(254), parity 0
    const int p_h1_w = 256 + 128;  // h1(255), parity 1
    short8 hp[4], h1p[4];
    #pragma unroll
    for (int kb=0;kb<4;kb++) hp[kb]  = *(const short8*)&Abuf[col][p_h0_r + kb*32 + lq*8];
    #pragma unroll
    for (int kb=0;kb<4;kb++) h1p[kb] = *(const short8*)&Abuf[col][p_h1_r + kb*32 + lq*8];
    float4v acc1[8];
    #pragma unroll
    for (int j=0;j<8;j++){
      float4v a = {bs1[j],bs1[j],bs1[j],bs1[j]};
      #pragma unroll
      for (int kb=0;kb<4;kb++) a = MFMA_B16(hp[kb],  as_s8(W1r[j][kb]),   a);
      #pragma unroll
      for (int kb=0;kb<4;kb++) a = MFMA_B16(h1p[kb], as_s8(W1r[j][kb+4]), a);
      acc1[j] = a;
    }
    #pragma unroll
    for (int p=0;p<2;p++)
      #pragma unroll
      for (int q=0;q<4;q++){
        float cc = fast_sigm(acc1[2+p][q])*c1[p*4+q]
                 + fast_sigm(acc1[p][q])*fast_tanh(acc1[4+p][q]);
        c1[p*4+q] = cc;
        Abuf[lq*4+q][p_h1_w + (2*w+p)*16 + col] = f2bf(fast_sigm(acc1[6+p][q])*fast_tanh(cc));
      }
    __syncthreads();
  }

  // ---- swap weights to decoder ----
  for (int i = tid; i < 2048; i += 256) Wx[i] = decW0[(size_t)(i>>6)*320 + (i&63)];
  for (int i = tid; i < 512;  i += 256) Wlin[i] = linT[i];
  #pragma unroll
  for (int j=0;j<8;j++){
    int nt = 8*(j>>1) + 2*w + (j&1);
    #pragma unroll
    for (int kb=0;kb<4;kb++) W0h[j][kb] = decW0[(size_t)nt*320 + (size_t)(kb+1)*64 + l];
    #pragma unroll
    for (int kb=0;kb<4;kb++) W1r[j][kb]   = ((const int4v*)decW1lo)[(size_t)nt*256 + (size_t)kb*64 + l];
    #pragma unroll
    for (int kb=0;kb<4;kb++) W1r[j][kb+4] = ((const int4v*)decW1hi)[(size_t)nt*256 + (size_t)kb*64 + l];
    bs0[j] = biases[1024 + nt*16 + col];
    bs1[j] = biases[1536 + nt*16 + col];
  }
  #pragma unroll
  for (int j=0;j<8;j++)
    #pragma unroll
    for (int kb=0;kb<8;kb++)
      asm volatile("" : "+a"(W1r[j][kb]));
  float blin = (w < 2) ? biases[2048 + w*16 + col] : 0.f;
  if (w == 0){
    *(short8*)&inpA[col][lq*8] = xf[(size_t)(T_-1)*64];   // dec input 0 = x[:,-1,:]
  }
  __syncthreads();

  // ---------------- decoder: 64 steps, 3 phases ----------------
  // enc left h0/h1 at parity 1 -> dec td reads parity (td+1)&1, writes td&1.
  #pragma unroll 2
  for (int td = 0; td < TGT; td++){
    const int h0r = ((td+1)&1) * 128;
    const int h0w = 128 - h0r;
    const int h1r = 256 + h0r;
    const int h1w = 256 + h0w;

    // ---- phase 1: layer 0 ----
    short8 a0d = *(const short8*)&inpA[col][lq*8];
    short8 hp[4];
    #pragma unroll
    for (int kb=0;kb<4;kb++) hp[kb] = *(const short8*)&Abuf[col][h0r + kb*32 + lq*8];
    float4v acc0[8];
    #pragma unroll
    for (int j=0;j<8;j++){
      float4v a = {bs0[j],bs0[j],bs0[j],bs0[j]};
      a = MFMA_B16(a0d, Wx[wxbase + (j>>1)*512 + (j&1)*64], a);
      #pragma unroll
      for (int kb=0;kb<4;kb++) a = MFMA_B16(hp[kb], W0h[j][kb], a);
      acc0[j] = a;
    }
    #pragma unroll
    for (int p=0;p<2;p++)
      #pragma unroll
      for (int q=0;q<4;q++){
        float cc = fast_sigm(acc0[2+p][q])*c0[p*4+q]
                 + fast_sigm(acc0[p][q])*fast_tanh(acc0[4+p][q]);
        c0[p*4+q] = cc;
        Abuf[lq*4+q][h0w + (2*w+p)*16 + col] = f2bf(fast_sigm(acc0[6+p][q])*fast_tanh(cc));
      }
    __syncthreads();

    // ---- phase 2: layer 1 ----
    short8 a1lo[4], a1hi[4];
    #pragma unroll
    for (int kb=0;kb<4;kb++) a1lo[kb] = *(const short8*)&Abuf[col][h0w + kb*32 + lq*8];
    #pragma unroll
    for (int kb=0;kb<4;kb++) a1hi[kb] = *(const short8*)&Abuf[col][h1r + kb*32 + lq*8];
    float4v acc1[8];
    #pragma unroll
    for (int j=0;j<8;j++){
      float4v a = {bs1[j],bs1[j],bs1[j],bs1[j]};
      #pragma unroll
      for (int kb=0;kb<4;kb++) a = MFMA_B16(a1lo[kb], as_s8(W1r[j][kb]),   a);
      #pragma unroll
      for (int kb=0;kb<4;kb++) a = MFMA_B16(a1hi[kb], as_s8(W1r[j][kb+4]), a);
      acc1[j] = a;
    }
    #pragma unroll
    for (int p=0;p<2;p++)
      #pragma unroll
      for (int q=0;q<4;q++){
        float cc = fast_sigm(acc1[2+p][q])*c1[p*4+q]
                 + fast_sigm(acc1[p][q])*fast_tanh(acc1[4+p][q]);
        c1[p*4+q] = cc;
        Abuf[lq*4+q][h1w + (2*w+p)*16 + col] = f2bf(fast_sigm(acc1[6+p][q])*fast_tanh(cc));
      }
    __syncthreads();

    // ---- phase 3: projection + feedback ----
    if (w < 2){
      short8 hf[4];
      #pragma unroll
      for (int kb=0;kb<4;kb++) hf[kb] = *(const short8*)&Abuf[col][h1w + kb*32 + lq*8];
      float4v a = {blin,blin,blin,blin};
      #pragma unroll
      for (int kb=0;kb<4;kb++) a = MFMA_B16(hf[kb], Wlin[(w*4+kb)*64 + l], a);
      #pragma unroll
      for (int q=0;q<4;q++){
        float v = a[q];
        int b = bblk*16 + lq*4 + q;
        out[((size_t)b*TGT + td)*DIN + (w*16 + col)] = v;
        inpA[lq*4+q][w*16 + col] = f2bf(v);
      }
    }
    __syncthreads();
  }
}

// ---------------- host ----------------
extern "C" void kernel_launch(void* const* d_in, const int* in_sizes, int n_in,
                              void* d_out, int out_size, void* d_ws, size_t ws_size,
                              hipStream_t stream) {
  const float* x      = (const float*)d_in[0];
  const float* eWih0  = (const float*)d_in[2];
  const float* eWhh0  = (const float*)d_in[3];
  const float* eb0a   = (const float*)d_in[4];
  const float* eb0b   = (const float*)d_in[5];
  const float* eWih1  = (const float*)d_in[6];
  const float* eWhh1  = (const float*)d_in[7];
  const float* eb1a   = (const float*)d_in[8];
  const float* eb1b   = (const float*)d_in[9];
  const float* dWih0  = (const float*)d_in[10];
  const float* dWhh0  = (const float*)d_in[11];
  const float* db0a   = (const float*)d_in[12];
  const float* db0b   = (const float*)d_in[13];
  const float* dWih1  = (const float*)d_in[14];
  const float* dWhh1  = (const float*)d_in[15];
  const float* db1a   = (const float*)d_in[16];
  const float* db1b   = (const float*)d_in[17];
  const float* linW   = (const float*)d_in[18];
  const float* linb   = (const float*)d_in[19];

  char* ws = (char*)d_ws;
  short8* xfrag   = (short8*)(ws + OFF_XFRAG);
  short8* encW0   = (short8*)(ws + OFF_EW0);
  short8* encW1lo = (short8*)(ws + OFF_EW1LO);
  short8* encW1hi = (short8*)(ws + OFF_EW1HI);
  short8* decW0   = (short8*)(ws + OFF_DW0);
  short8* decW1lo = (short8*)(ws + OFF_DW1LO);
  short8* decW1hi = (short8*)(ws + OFF_DW1HI);
  short8* linT    = (short8*)(ws + OFF_LIN);
  float*  biases  = (float*)(ws + OFF_BIAS);

  prep_x_kernel<<<2048, 256, 0, stream>>>(x, xfrag);
  prep_w_kernel<<<219, 256, 0, stream>>>(
      eWih0,eWhh0,eWih1,eWhh1,dWih0,dWhh0,dWih1,dWhh1,linW,
      eb0a,eb0b,eb1a,eb1b,db0a,db0b,db1a,db1b,linb,
      encW0,encW1lo,encW1hi,decW0,decW1lo,decW1hi,linT,biases);
  lstm_main_kernel<<<32, 256, 0, stream>>>(
      xfrag, encW0, encW1lo, encW1hi, decW0, decW1lo, decW1hi,
      linT, biases, (float*)d_out);
}